// Round 15
// baseline (80.523 us; speedup 1.0000x reference)
//
#include <hip/hip_runtime.h>
#include <hip/hip_bf16.h>
#include <cmath>

#define LATENTS 64
#define HID 64
#define IN_DIM 65
#define SLOPE 0.2f
#define FEPS 1e-8f
#define RPB 128            // rows per chunk: 8 waves x 1 tile x 16 rows
#define CHUNKS 4           // chunks per block; weights staged once per block
#define WBYTES 53248       // per-latent pre-split weights: 3*16KB (W0-2) + 4KB (W3)
#define W65_BYTE (64 * WBYTES)

// channel a = act*16+au*4+ai  ->  slot s = (act&1)*32 + au*8 + (act>>1)*4 + ai
#define A_OF_SLOT(s) ((((((s) >> 2) & 1) * 2 + ((s) >> 5)) * 16) + ((((s) >> 3) & 3) * 4) + ((s) & 3))

typedef __attribute__((ext_vector_type(8))) short short8;
typedef __attribute__((ext_vector_type(4))) float f32x4;
typedef __attribute__((address_space(1))) const unsigned GASU;
typedef __attribute__((address_space(3))) unsigned LASU;

__device__ __forceinline__ unsigned asu(float f){ return __builtin_bit_cast(unsigned, f); }
__device__ __forceinline__ float    asf(unsigned u){ return __builtin_bit_cast(float, u); }
__device__ __forceinline__ unsigned bfu(float f){
    return (unsigned)__builtin_bit_cast(unsigned short, __float2bfloat16(f));
}

// w_prep split: hi = trunc16, lo = RTNE(remainder)  (R12/R13-measured numerics)
__device__ __forceinline__ void split8v(const float* f, short8& hi, short8& lo){
    unsigned hw[4], lw[4];
#pragma unroll
    for (int w = 0; w < 4; ++w){
        float a = f[2 * w], b = f[2 * w + 1];
        unsigned ha = asu(a) & 0xFFFF0000u, hb = asu(b) & 0xFFFF0000u;
        float la = a - asf(ha), lb = b - asf(hb);
        hw[w] = (ha >> 16) | hb;
        lw[w] = bfu(la) | (bfu(lb) << 16);
    }
    uint4 h4{hw[0], hw[1], hw[2], hw[3]}, l4{lw[0], lw[1], lw[2], lw[3]};
    hi = __builtin_bit_cast(short8, h4);
    lo = __builtin_bit_cast(short8, l4);
}

// hot path: hi = trunc16(f), lo = round-half-up16(f - hi)
__device__ __forceinline__ void split8t(const float* f, short8& hi, short8& lo){
    unsigned hw[4], lw[4];
#pragma unroll
    for (int w = 0; w < 4; ++w){
        float a = f[2 * w], b = f[2 * w + 1];
        float la = a - asf(asu(a) & 0xFFFF0000u);
        float lb = b - asf(asu(b) & 0xFFFF0000u);
        hw[w] = __builtin_amdgcn_perm(asu(b), asu(a), 0x07060302u);
        lw[w] = __builtin_amdgcn_perm(asu(lb) + 0x8000u, asu(la) + 0x8000u, 0x07060302u);
    }
    uint4 h4{hw[0], hw[1], hw[2], hw[3]}, l4{lw[0], lw[1], lw[2], lw[3]};
    hi = __builtin_bit_cast(short8, h4);
    lo = __builtin_bit_cast(short8, l4);
}

// round-half-up pack (tangent storage): add + perm per pair
__device__ __forceinline__ short8 pack8r(const float* f){
    unsigned w[4];
#pragma unroll
    for (int i = 0; i < 4; ++i)
        w[i] = __builtin_amdgcn_perm(asu(f[2 * i + 1]) + 0x8000u,
                                     asu(f[2 * i])     + 0x8000u, 0x07060302u);
    uint4 p{w[0], w[1], w[2], w[3]};
    return __builtin_bit_cast(short8, p);
}

__device__ __forceinline__ f32x4 mfma_(short8 a, short8 b, f32x4 c){
    return __builtin_amdgcn_mfma_f32_16x16x32_bf16(a, b, c, 0, 0, 0);
}

__global__ void lad_init_kernel(float* __restrict__ lad, int n){
    int i = blockIdx.x * blockDim.x + threadIdx.x;
    if (i < n) lad[i] = 0.0f;
}

// Pre-split all weights into hi/lo bf16 MFMA fragments, laid out per-latent as one
// contiguous 52KB block (hi-plane / lo-plane separated for 16B-stride ds_reads).
__global__ __launch_bounds__(64)
void w_prep_kernel(const float* __restrict__ W0, const float* __restrict__ W1,
                   const float* __restrict__ W2, const float* __restrict__ W3,
                   char* __restrict__ ws)
{
    const int b = blockIdx.x;
    const int L = threadIdx.x;
    const int c  = L & 15;
    const int kb = (L >> 4) * 8;
    if (b < 192){                        // W0/W1/W2 fragments
        const int l = b / 3, d = b - 3 * l;
        const float* Wd = (d == 0) ? W0 + (size_t)l * 64 * IN_DIM
                        : (d == 1) ? W1 + (size_t)l * 4096
                                   : W2 + (size_t)l * 4096;
        const int K = (d == 0) ? IN_DIM : 64;
#pragma unroll
        for (int ks = 0; ks < 2; ++ks)
#pragma unroll
            for (int ct = 0; ct < 4; ++ct){
                float wf[8];
#pragma unroll
                for (int j = 0; j < 8; ++j){
                    const int s = ks * 32 + kb + j;
                    const int a = (d == 0) ? s : A_OF_SLOT(s);
                    wf[j] = Wd[(size_t)(ct * 16 + c) * K + a];
                }
                short8 wh, wl;
                split8v(wf, wh, wl);
                char* base = ws + (size_t)l * WBYTES + d * 16384 + (ks * 4 + ct) * 1024 + L * 16;
                *(short8*)base            = wh;
                *(short8*)(base + 8192)   = wl;
            }
    } else {                             // W3 fragments + w65 table
        const int l = b - 192;
#pragma unroll
        for (int ks = 0; ks < 2; ++ks){
            float wf[8];
#pragma unroll
            for (int j = 0; j < 8; ++j)
                wf[j] = (c == 0) ? W3[l * 64 + A_OF_SLOT(ks * 32 + kb + j)] : 0.0f;
            short8 wh, wl;
            split8v(wf, wh, wl);
            char* base = ws + (size_t)l * WBYTES + 49152 + ks * 1024 + L * 16;
            *(short8*)base          = wh;
            *(short8*)(base + 2048) = wl;
        }
        ((float*)(ws + W65_BYTE))[l * 64 + L] =
            W0[(size_t)l * 64 * IN_DIM + L * IN_DIM + 64];
    }
}

__global__ __launch_bounds__(512, 4)
void flow_mfma_kernel(const float* __restrict__ x,
                      const float* __restrict__ b0, const float* __restrict__ b1,
                      const float* __restrict__ b2, const float* __restrict__ b3,
                      const char* __restrict__ ws,
                      float* __restrict__ out_res, float* __restrict__ out_lad)
{
    __shared__ __attribute__((aligned(16))) char wlds[WBYTES];

    const int l     = blockIdx.y;
    const int tid   = threadIdx.x;
    const int L     = tid & 63;
    const int wv    = tid >> 6;
    const int u     = L >> 4;
    const int rbase = blockIdx.x * (RPB * CHUNKS) + wv * 16 + (L & 15);

    // ---- stage this latent's 52KB weight block into LDS, ONCE per block ----
    const char* gsrc = ws + (size_t)l * WBYTES;
#pragma unroll
    for (int i = 0; i < 7; ++i){
        const int base = i * 512 + wv * 64;          // wave-uniform chunk base
        if (base * 16 < WBYTES)
            __builtin_amdgcn_global_load_lds((GASU*)(gsrc + (base + L) * 16),
                                             (LASU*)(wlds + base * 16), 16, 0, 0);
    }

    // ---- x loaders / splitters (rolling A/B prefetch buffers) ----
    auto loadx = [&](float (&xv)[16], float& x65, int c){
        const float* xg = x + ((size_t)(rbase + c * RPB) * LATENTS + l) * IN_DIM;
#pragma unroll
        for (int j = 0; j < 8; ++j){
            xv[j]     = xg[8 * u + j];
            xv[8 + j] = xg[32 + 8 * u + j];
        }
        x65 = xg[64];
    };

    short8 bh[2], bl2[2], th2[2];
    auto splitx = [&](const float (&xv)[16]){
        split8t(&xv[0], bh[0], bl2[0]);
        split8t(&xv[8], bh[1], bl2[1]);
    };

    auto ldw = [&](int d, int ks, int ct, short8& wh, short8& wl){
        const char* p = wlds + d * 16384 + (ks * 4 + ct) * 1024 + (L << 4);
        wh = *(const short8*)p;
        wl = *(const short8*)(p + 8192);
    };
    // h-epilogue repack (channel->slot permutation, trunc hi / rhup lo)
    auto repack = [&](const float v[4][4]){
#pragma unroll
        for (int ks = 0; ks < 2; ++ks){
            float f8[8] = {v[ks][0], v[ks][1], v[ks][2], v[ks][3],
                           v[2 + ks][0], v[2 + ks][1], v[2 + ks][2], v[2 + ks][3]};
            split8t(f8, bh[ks], bl2[ks]);
        }
    };
    // t-epilogue repack (rhup bf16)
    auto repackt = [&](const float v[4][4]){
#pragma unroll
        for (int ks = 0; ks < 2; ++ks){
            float f8[8] = {v[ks][0], v[ks][1], v[ks][2], v[ks][3],
                           v[2 + ks][0], v[2 + ks][1], v[2 + ks][2], v[2 + ks][3]};
            th2[ks] = pack8r(f8);
        }
    };

    // ---- one chunk's full network (uses bh/bl2 set by splitx) ----
    auto run = [&](int c, float x65r){
        const int g0 = rbase + c * RPB;
        f32x4 ha[4], ta[4];

        // layer 0 (h only) + rank-1 col-64; tangent = mask * w65
        {
#pragma unroll
            for (int ct = 0; ct < 4; ++ct)
                ha[ct] = __builtin_bit_cast(f32x4,
                            *(const float4*)(b0 + l * 64 + ct * 16 + u * 4));
#pragma unroll
            for (int ks = 0; ks < 2; ++ks){
#pragma unroll
                for (int ct = 0; ct < 4; ++ct){
                    short8 wh, wl;
                    ldw(0, ks, ct, wh, wl);
                    __builtin_amdgcn_s_setprio(1);
                    ha[ct] = mfma_(wh, bh[ks],  ha[ct]);
                    ha[ct] = mfma_(wh, bl2[ks], ha[ct]);
                    ha[ct] = mfma_(wl, bh[ks],  ha[ct]);
                    __builtin_amdgcn_s_setprio(0);
                }
            }
            const float* w65p = (const float*)(ws + W65_BYTE) + l * 64;
            float hv[4][4], tv[4][4];
#pragma unroll
            for (int ct = 0; ct < 4; ++ct){
                const float4 wv4 = *(const float4*)(w65p + ct * 16 + u * 4);
                const float wa[4] = {wv4.x, wv4.y, wv4.z, wv4.w};
#pragma unroll
                for (int i = 0; i < 4; ++i){
                    float z = fmaf(x65r, wa[i], ha[ct][i]);
                    float m = (z >= 0.0f) ? 1.0f : SLOPE;
                    hv[ct][i] = z * m;
                    tv[ct][i] = wa[i] * m;
                }
            }
            repack(hv);
            repackt(tv);
        }

        // layers 1,2: h (split, 3 MFMA) + t (2 MFMA)
        auto dense2 = [&](int d, const float* __restrict__ bl){
#pragma unroll
            for (int ct = 0; ct < 4; ++ct){
                ha[ct] = __builtin_bit_cast(f32x4,
                            *(const float4*)(bl + ct * 16 + u * 4));
                ta[ct] = (f32x4){0.f, 0.f, 0.f, 0.f};
            }
#pragma unroll
            for (int ks = 0; ks < 2; ++ks){
#pragma unroll
                for (int ct = 0; ct < 4; ++ct){
                    short8 wh, wl;
                    ldw(d, ks, ct, wh, wl);
                    __builtin_amdgcn_s_setprio(1);
                    ha[ct] = mfma_(wh, bh[ks],  ha[ct]);
                    ha[ct] = mfma_(wh, bl2[ks], ha[ct]);
                    ha[ct] = mfma_(wl, bh[ks],  ha[ct]);
                    ta[ct] = mfma_(wh, th2[ks], ta[ct]);
                    ta[ct] = mfma_(wl, th2[ks], ta[ct]);
                    __builtin_amdgcn_s_setprio(0);
                }
            }
            float hv[4][4], tv[4][4];
#pragma unroll
            for (int ct = 0; ct < 4; ++ct)
#pragma unroll
                for (int i = 0; i < 4; ++i){
                    float z  = ha[ct][i];
                    float zt = ta[ct][i];
                    float m  = (z >= 0.0f) ? 1.0f : SLOPE;
                    hv[ct][i] = z * m;
                    tv[ct][i] = zt * m;
                }
            repack(hv);
            repackt(tv);
        };
        dense2(1, b1 + l * 64);
        dense2(2, b2 + l * 64);

        // layer 3: scalar head via MFMA (w3 in fragment col 0)
        {
            f32x4 so = (f32x4){0.f, 0.f, 0.f, 0.f};
            f32x4 sd = (f32x4){0.f, 0.f, 0.f, 0.f};
#pragma unroll
            for (int ks = 0; ks < 2; ++ks){
                const char* p = wlds + 49152 + ks * 1024 + (L << 4);
                short8 wh = *(const short8*)p;
                short8 wl = *(const short8*)(p + 2048);
                __builtin_amdgcn_s_setprio(1);
                so = mfma_(wh, bh[ks],  so);
                so = mfma_(wh, bl2[ks], so);
                so = mfma_(wl, bh[ks],  so);
                sd = mfma_(wh, th2[ks], sd);
                sd = mfma_(wl, th2[ks], sd);
                __builtin_amdgcn_s_setprio(0);
            }
            if (u == 0){   // D row 0 (lanes 0-15, reg 0); col = batch row
                out_res[(size_t)g0 * LATENTS + l] = so[0] + b3[l];
                atomicAdd(&out_lad[g0], __logf(fabsf(sd[0]) + FEPS));
            }
        }
    };

    // ---- 4-chunk schedule with rolling x prefetch ----
    float xvA[16], xvB[16];
    float x650, x651, x652, x653;
    loadx(xvA, x650, 0);          // chunks 0,1 x-loads hide under staging barrier
    loadx(xvB, x651, 1);
    __syncthreads();              // weights resident in LDS

    splitx(xvA);
    loadx(xvA, x652, 2);          // prefetch chunk 2 (covered by chunks 0-1 compute)
    run(0, x650);
    splitx(xvB);
    loadx(xvB, x653, 3);          // prefetch chunk 3 (covered by chunks 1-2 compute)
    run(1, x651);
    splitx(xvA);
    run(2, x652);
    splitx(xvB);
    run(3, x653);
}

extern "C" void kernel_launch(void* const* d_in, const int* in_sizes, int n_in,
                              void* d_out, int out_size, void* d_ws, size_t ws_size,
                              hipStream_t stream)
{
    const float* x  = (const float*)d_in[0];
    const float* W0 = (const float*)d_in[1];
    const float* b0 = (const float*)d_in[2];
    const float* W1 = (const float*)d_in[3];
    const float* b1 = (const float*)d_in[4];
    const float* W2 = (const float*)d_in[5];
    const float* b2 = (const float*)d_in[6];
    const float* W3 = (const float*)d_in[7];
    const float* b3 = (const float*)d_in[8];

    const int B = in_sizes[0] / (LATENTS * IN_DIM);  // 8192
    float* out_res = (float*)d_out;
    float* out_lad = out_res + (size_t)B * LATENTS;
    char*  wsp     = (char*)d_ws;   // 64*52KB frags + 16KB w65 = 3.27 MB

    lad_init_kernel<<<dim3((B + 255) / 256), dim3(256), 0, stream>>>(out_lad, B);
    w_prep_kernel<<<dim3(256), dim3(64), 0, stream>>>(W0, W1, W2, W3, wsp);
    flow_mfma_kernel<<<dim3(B / (RPB * CHUNKS), LATENTS), dim3(512), 0, stream>>>(
        x, b0, b1, b2, b3, wsp, out_res, out_lad);
}

// Round 16
// 75.167 us; speedup vs baseline: 1.0713x; 1.0713x over previous
//
#include <hip/hip_runtime.h>
#include <hip/hip_bf16.h>
#include <cmath>

#define LATENTS 64
#define HID 64
#define IN_DIM 65
#define SLOPE 0.2f
#define FEPS 1e-8f
#define RPB 128            // rows per block: 8 waves x 1 tile x 16 rows
#define WBYTES 53248       // per-latent pre-split weights: 3*16KB (W0-2) + 4KB (W3)
#define W65_BYTE (64 * WBYTES)

// channel a = act*16+au*4+ai  ->  slot s = (act&1)*32 + au*8 + (act>>1)*4 + ai
#define A_OF_SLOT(s) ((((((s) >> 2) & 1) * 2 + ((s) >> 5)) * 16) + ((((s) >> 3) & 3) * 4) + ((s) & 3))

typedef __attribute__((ext_vector_type(8))) short short8;
typedef __attribute__((ext_vector_type(4))) float f32x4;
typedef __attribute__((address_space(1))) const unsigned GASU;
typedef __attribute__((address_space(3))) unsigned LASU;

__device__ __forceinline__ unsigned asu(float f){ return __builtin_bit_cast(unsigned, f); }
__device__ __forceinline__ float    asf(unsigned u){ return __builtin_bit_cast(float, u); }
__device__ __forceinline__ unsigned bfu(float f){
    return (unsigned)__builtin_bit_cast(unsigned short, __float2bfloat16(f));
}

// RTNE split (w_prep only — runs once, precision for weights)
__device__ __forceinline__ void split8v(const float* f, short8& hi, short8& lo){
    unsigned hw[4], lw[4];
#pragma unroll
    for (int w = 0; w < 4; ++w){
        float a = f[2 * w], b = f[2 * w + 1];
        unsigned ha = asu(a) & 0xFFFF0000u, hb = asu(b) & 0xFFFF0000u;
        float la = a - asf(ha), lb = b - asf(hb);
        hw[w] = (ha >> 16) | hb;
        lw[w] = bfu(la) | (bfu(lb) << 16);
    }
    uint4 h4{hw[0], hw[1], hw[2], hw[3]}, l4{lw[0], lw[1], lw[2], lw[3]};
    hi = __builtin_bit_cast(short8, h4);
    lo = __builtin_bit_cast(short8, l4);
}

// hot path: hi = trunc16(f), lo = round-half-up16(f - hi)
__device__ __forceinline__ void split8t(const float* f, short8& hi, short8& lo){
    unsigned hw[4], lw[4];
#pragma unroll
    for (int w = 0; w < 4; ++w){
        float a = f[2 * w], b = f[2 * w + 1];
        float la = a - asf(asu(a) & 0xFFFF0000u);
        float lb = b - asf(asu(b) & 0xFFFF0000u);
        hw[w] = __builtin_amdgcn_perm(asu(b), asu(a), 0x07060302u);
        lw[w] = __builtin_amdgcn_perm(asu(lb) + 0x8000u, asu(la) + 0x8000u, 0x07060302u);
    }
    uint4 h4{hw[0], hw[1], hw[2], hw[3]}, l4{lw[0], lw[1], lw[2], lw[3]};
    hi = __builtin_bit_cast(short8, h4);
    lo = __builtin_bit_cast(short8, l4);
}

// round-half-up pack (tangent storage): add + perm per pair
__device__ __forceinline__ short8 pack8r(const float* f){
    unsigned w[4];
#pragma unroll
    for (int i = 0; i < 4; ++i)
        w[i] = __builtin_amdgcn_perm(asu(f[2 * i + 1]) + 0x8000u,
                                     asu(f[2 * i])     + 0x8000u, 0x07060302u);
    uint4 p{w[0], w[1], w[2], w[3]};
    return __builtin_bit_cast(short8, p);
}

__device__ __forceinline__ f32x4 mfma_(short8 a, short8 b, f32x4 c){
    return __builtin_amdgcn_mfma_f32_16x16x32_bf16(a, b, c, 0, 0, 0);
}

// Pre-split all weights into hi/lo bf16 MFMA fragments (52KB/latent), and
// zero-init the logabsdet output (blocks 256..383) — one launch does both.
__global__ __launch_bounds__(64)
void w_prep_kernel(const float* __restrict__ W0, const float* __restrict__ W1,
                   const float* __restrict__ W2, const float* __restrict__ W3,
                   char* __restrict__ ws, float* __restrict__ lad, int B)
{
    const int b = blockIdx.x;
    const int L = threadIdx.x;
    const int c  = L & 15;
    const int kb = (L >> 4) * 8;
    if (b >= 256){                       // lad zero-init
        const int i = (b - 256) * 64 + L;
        if (i < B) lad[i] = 0.0f;
        return;
    }
    if (b < 192){                        // W0/W1/W2 fragments
        const int l = b / 3, d = b - 3 * l;
        const float* Wd = (d == 0) ? W0 + (size_t)l * 64 * IN_DIM
                        : (d == 1) ? W1 + (size_t)l * 4096
                                   : W2 + (size_t)l * 4096;
        const int K = (d == 0) ? IN_DIM : 64;
#pragma unroll
        for (int ks = 0; ks < 2; ++ks)
#pragma unroll
            for (int ct = 0; ct < 4; ++ct){
                float wf[8];
#pragma unroll
                for (int j = 0; j < 8; ++j){
                    const int s = ks * 32 + kb + j;
                    const int a = (d == 0) ? s : A_OF_SLOT(s);
                    wf[j] = Wd[(size_t)(ct * 16 + c) * K + a];
                }
                short8 wh, wl;
                split8v(wf, wh, wl);
                char* base = ws + (size_t)l * WBYTES + d * 16384 + (ks * 4 + ct) * 1024 + L * 16;
                *(short8*)base            = wh;
                *(short8*)(base + 8192)   = wl;
            }
    } else {                             // W3 fragments + w65 table
        const int l = b - 192;
#pragma unroll
        for (int ks = 0; ks < 2; ++ks){
            float wf[8];
#pragma unroll
            for (int j = 0; j < 8; ++j)
                wf[j] = (c == 0) ? W3[l * 64 + A_OF_SLOT(ks * 32 + kb + j)] : 0.0f;
            short8 wh, wl;
            split8v(wf, wh, wl);
            char* base = ws + (size_t)l * WBYTES + 49152 + ks * 1024 + L * 16;
            *(short8*)base          = wh;
            *(short8*)(base + 2048) = wl;
        }
        ((float*)(ws + W65_BYTE))[l * 64 + L] =
            W0[(size_t)l * 64 * IN_DIM + L * IN_DIM + 64];
    }
}

__global__ __launch_bounds__(512, 4)
void flow_mfma_kernel(const float* __restrict__ x,
                      const float* __restrict__ b0, const float* __restrict__ b1,
                      const float* __restrict__ b2, const float* __restrict__ b3,
                      const char* __restrict__ ws,
                      float* __restrict__ out_res, float* __restrict__ out_lad)
{
    __shared__ __attribute__((aligned(16))) char wlds[WBYTES];

    const int l   = blockIdx.y;
    const int tid = threadIdx.x;
    const int L   = tid & 63;
    const int wv  = tid >> 6;
    const int u   = L >> 4;
    const int g0  = blockIdx.x * RPB + wv * 16 + (L & 15);  // this lane's batch row

    // ---- stage this latent's 52KB weight block into LDS (8 waves cooperate) ----
    const char* gsrc = ws + (size_t)l * WBYTES;
#pragma unroll
    for (int i = 0; i < 7; ++i){
        const int base = i * 512 + wv * 64;          // wave-uniform chunk base
        if (base * 16 < WBYTES)
            __builtin_amdgcn_global_load_lds((GASU*)(gsrc + (base + L) * 16),
                                             (LASU*)(wlds + base * 16), 16, 0, 0);
    }

    // ---- per-lane x load at its own B-slots (overlap staging latency) ----
    const float* xg0 = x + ((size_t)g0 * LATENTS + l) * IN_DIM;
    float xv[16];
    float x65r;
#pragma unroll
    for (int j = 0; j < 8; ++j){
        xv[j]     = xg0[8 * u + j];
        xv[8 + j] = xg0[32 + 8 * u + j];
    }
    x65r = xg0[64];

    // ---- split x into B-frags (trunc hi / rhup lo) ----
    short8 bh[2], bl2[2], th2[2];
    split8t(&xv[0], bh[0], bl2[0]);
    split8t(&xv[8], bh[1], bl2[1]);

    __syncthreads();   // weights resident in LDS

    f32x4 ha[4], ta[4];

    auto ldw = [&](int d, int ks, int ct, short8& wh, short8& wl){
        const char* p = wlds + d * 16384 + (ks * 4 + ct) * 1024 + (L << 4);
        wh = *(const short8*)p;
        wl = *(const short8*)(p + 8192);
    };
    // h-epilogue repack (channel->slot permutation, trunc hi / rhup lo)
    auto repack = [&](const float v[4][4], short8 (&hi)[2], short8 (&lo)[2]){
#pragma unroll
        for (int ks = 0; ks < 2; ++ks){
            float f8[8] = {v[ks][0], v[ks][1], v[ks][2], v[ks][3],
                           v[2 + ks][0], v[2 + ks][1], v[2 + ks][2], v[2 + ks][3]};
            split8t(f8, hi[ks], lo[ks]);
        }
    };
    // t-epilogue repack (rhup bf16 only)
    auto repackt = [&](const float v[4][4], short8 (&hi)[2]){
#pragma unroll
        for (int ks = 0; ks < 2; ++ks){
            float f8[8] = {v[ks][0], v[ks][1], v[ks][2], v[ks][3],
                           v[2 + ks][0], v[2 + ks][1], v[2 + ks][2], v[2 + ks][3]};
            hi[ks] = pack8r(f8);
        }
    };

    // ---- layer 0 (h only) + rank-1 col-64; tangent = mask * w65 ----
    {
#pragma unroll
        for (int ct = 0; ct < 4; ++ct)
            ha[ct] = __builtin_bit_cast(f32x4,
                        *(const float4*)(b0 + l * 64 + ct * 16 + u * 4));
#pragma unroll
        for (int ks = 0; ks < 2; ++ks){
#pragma unroll
            for (int ct = 0; ct < 4; ++ct){
                short8 wh, wl;
                ldw(0, ks, ct, wh, wl);
                __builtin_amdgcn_s_setprio(1);
                ha[ct] = mfma_(wh, bh[ks],  ha[ct]);
                ha[ct] = mfma_(wh, bl2[ks], ha[ct]);
                ha[ct] = mfma_(wl, bh[ks],  ha[ct]);
                __builtin_amdgcn_s_setprio(0);
            }
        }
        const float* w65p = (const float*)(ws + W65_BYTE) + l * 64;
        float hv[4][4], tv[4][4];
#pragma unroll
        for (int ct = 0; ct < 4; ++ct){
            const float4 wv4 = *(const float4*)(w65p + ct * 16 + u * 4);
            const float wa[4] = {wv4.x, wv4.y, wv4.z, wv4.w};
#pragma unroll
            for (int i = 0; i < 4; ++i){
                float z = fmaf(x65r, wa[i], ha[ct][i]);
                float m = (z >= 0.0f) ? 1.0f : SLOPE;
                hv[ct][i] = z * m;
                tv[ct][i] = wa[i] * m;
            }
        }
        repack(hv, bh, bl2);
        repackt(tv, th2);
    }

    // ---- layers 1,2: h (split) + t (bf16) GEMMs, weights JIT from LDS ----
    auto dense2 = [&](int d, const float* __restrict__ bl){
#pragma unroll
        for (int ct = 0; ct < 4; ++ct){
            ha[ct] = __builtin_bit_cast(f32x4,
                        *(const float4*)(bl + ct * 16 + u * 4));
            ta[ct] = (f32x4){0.f, 0.f, 0.f, 0.f};
        }
#pragma unroll
        for (int ks = 0; ks < 2; ++ks){
#pragma unroll
            for (int ct = 0; ct < 4; ++ct){
                short8 wh, wl;
                ldw(d, ks, ct, wh, wl);
                __builtin_amdgcn_s_setprio(1);
                ha[ct] = mfma_(wh, bh[ks],  ha[ct]);
                ha[ct] = mfma_(wh, bl2[ks], ha[ct]);
                ha[ct] = mfma_(wl, bh[ks],  ha[ct]);
                ta[ct] = mfma_(wh, th2[ks], ta[ct]);
                ta[ct] = mfma_(wl, th2[ks], ta[ct]);
                __builtin_amdgcn_s_setprio(0);
            }
        }
        float hv[4][4], tv[4][4];
#pragma unroll
        for (int ct = 0; ct < 4; ++ct)
#pragma unroll
            for (int i = 0; i < 4; ++i){
                float z  = ha[ct][i];
                float zt = ta[ct][i];
                float m  = (z >= 0.0f) ? 1.0f : SLOPE;
                hv[ct][i] = z * m;
                tv[ct][i] = zt * m;
            }
        repack(hv, bh, bl2);
        repackt(tv, th2);
    };
    dense2(1, b1 + l * 64);
    dense2(2, b2 + l * 64);

    // ---- layer 3: scalar head via MFMA (w3 in fragment col 0) ----
    {
        f32x4 so = (f32x4){0.f, 0.f, 0.f, 0.f};
        f32x4 sd = (f32x4){0.f, 0.f, 0.f, 0.f};
#pragma unroll
        for (int ks = 0; ks < 2; ++ks){
            const char* p = wlds + 49152 + ks * 1024 + (L << 4);
            short8 wh = *(const short8*)p;
            short8 wl = *(const short8*)(p + 2048);
            __builtin_amdgcn_s_setprio(1);
            so = mfma_(wh, bh[ks],  so);
            so = mfma_(wh, bl2[ks], so);
            so = mfma_(wl, bh[ks],  so);
            sd = mfma_(wh, th2[ks], sd);
            sd = mfma_(wl, th2[ks], sd);
            __builtin_amdgcn_s_setprio(0);
        }
        if (u == 0){   // D row 0 (lanes 0-15, reg 0); col = batch row
            out_res[(size_t)g0 * LATENTS + l] = so[0] + b3[l];
            atomicAdd(&out_lad[g0], __logf(fabsf(sd[0]) + FEPS));
        }
    }
}

extern "C" void kernel_launch(void* const* d_in, const int* in_sizes, int n_in,
                              void* d_out, int out_size, void* d_ws, size_t ws_size,
                              hipStream_t stream)
{
    const float* x  = (const float*)d_in[0];
    const float* W0 = (const float*)d_in[1];
    const float* b0 = (const float*)d_in[2];
    const float* W1 = (const float*)d_in[3];
    const float* b1 = (const float*)d_in[4];
    const float* W2 = (const float*)d_in[5];
    const float* b2 = (const float*)d_in[6];
    const float* W3 = (const float*)d_in[7];
    const float* b3 = (const float*)d_in[8];

    const int B = in_sizes[0] / (LATENTS * IN_DIM);  // 8192
    float* out_res = (float*)d_out;
    float* out_lad = out_res + (size_t)B * LATENTS;
    char*  wsp     = (char*)d_ws;   // 64*52KB frags + 16KB w65 = 3.27 MB

    w_prep_kernel<<<dim3(256 + (B + 63) / 64), dim3(64), 0, stream>>>(
        W0, W1, W2, W3, wsp, out_lad, B);
    flow_mfma_kernel<<<dim3(B / RPB, LATENTS), dim3(512), 0, stream>>>(
        x, b0, b1, b2, b3, wsp, out_res, out_lad);
}

// Round 17
// 73.161 us; speedup vs baseline: 1.1006x; 1.0274x over previous
//
#include <hip/hip_runtime.h>
#include <hip/hip_bf16.h>
#include <cmath>

#define LATENTS 64
#define HID 64
#define IN_DIM 65
#define SLOPE 0.2f
#define FEPS 1e-8f
#define RPB 128            // rows per block: 8 waves x 1 tile x 16 rows
#define WBYTES 53248       // per-latent pre-split weights: 3*16KB (W0-2) + 4KB (W3)
#define W65_BYTE (64 * WBYTES)

// channel a = act*16+au*4+ai  ->  slot s = (act&1)*32 + au*8 + (act>>1)*4 + ai
#define A_OF_SLOT(s) ((((((s) >> 2) & 1) * 2 + ((s) >> 5)) * 16) + ((((s) >> 3) & 3) * 4) + ((s) & 3))

typedef __attribute__((ext_vector_type(8))) short short8;
typedef __attribute__((ext_vector_type(4))) float f32x4;
typedef __attribute__((address_space(1))) const unsigned GASU;
typedef __attribute__((address_space(3))) unsigned LASU;

__device__ __forceinline__ unsigned asu(float f){ return __builtin_bit_cast(unsigned, f); }
__device__ __forceinline__ float    asf(unsigned u){ return __builtin_bit_cast(float, u); }
__device__ __forceinline__ unsigned bfu(float f){
    return (unsigned)__builtin_bit_cast(unsigned short, __float2bfloat16(f));
}

// RTNE split (w_prep only — runs once, precision for weights)
__device__ __forceinline__ void split8v(const float* f, short8& hi, short8& lo){
    unsigned hw[4], lw[4];
#pragma unroll
    for (int w = 0; w < 4; ++w){
        float a = f[2 * w], b = f[2 * w + 1];
        unsigned ha = asu(a) & 0xFFFF0000u, hb = asu(b) & 0xFFFF0000u;
        float la = a - asf(ha), lb = b - asf(hb);
        hw[w] = (ha >> 16) | hb;
        lw[w] = bfu(la) | (bfu(lb) << 16);
    }
    uint4 h4{hw[0], hw[1], hw[2], hw[3]}, l4{lw[0], lw[1], lw[2], lw[3]};
    hi = __builtin_bit_cast(short8, h4);
    lo = __builtin_bit_cast(short8, l4);
}

// hot path: hi = trunc16(f), lo = round-half-up16(f - hi)
__device__ __forceinline__ void split8t(const float* f, short8& hi, short8& lo){
    unsigned hw[4], lw[4];
#pragma unroll
    for (int w = 0; w < 4; ++w){
        float a = f[2 * w], b = f[2 * w + 1];
        float la = a - asf(asu(a) & 0xFFFF0000u);
        float lb = b - asf(asu(b) & 0xFFFF0000u);
        hw[w] = __builtin_amdgcn_perm(asu(b), asu(a), 0x07060302u);
        lw[w] = __builtin_amdgcn_perm(asu(lb) + 0x8000u, asu(la) + 0x8000u, 0x07060302u);
    }
    uint4 h4{hw[0], hw[1], hw[2], hw[3]}, l4{lw[0], lw[1], lw[2], lw[3]};
    hi = __builtin_bit_cast(short8, h4);
    lo = __builtin_bit_cast(short8, l4);
}

// round-half-up pack (tangent storage): add + perm per pair
__device__ __forceinline__ short8 pack8r(const float* f){
    unsigned w[4];
#pragma unroll
    for (int i = 0; i < 4; ++i)
        w[i] = __builtin_amdgcn_perm(asu(f[2 * i + 1]) + 0x8000u,
                                     asu(f[2 * i])     + 0x8000u, 0x07060302u);
    uint4 p{w[0], w[1], w[2], w[3]};
    return __builtin_bit_cast(short8, p);
}

__device__ __forceinline__ f32x4 mfma_(short8 a, short8 b, f32x4 c){
    return __builtin_amdgcn_mfma_f32_16x16x32_bf16(a, b, c, 0, 0, 0);
}

// Pre-split all weights into hi/lo bf16 MFMA fragments (52KB/latent), and
// zero-init the logabsdet output (blocks 256..383) — one launch does both.
__global__ __launch_bounds__(64)
void w_prep_kernel(const float* __restrict__ W0, const float* __restrict__ W1,
                   const float* __restrict__ W2, const float* __restrict__ W3,
                   char* __restrict__ ws, float* __restrict__ lad, int B)
{
    const int b = blockIdx.x;
    const int L = threadIdx.x;
    const int c  = L & 15;
    const int kb = (L >> 4) * 8;
    if (b >= 256){                       // lad zero-init
        const int i = (b - 256) * 64 + L;
        if (i < B) lad[i] = 0.0f;
        return;
    }
    if (b < 192){                        // W0/W1/W2 fragments
        const int l = b / 3, d = b - 3 * l;
        const float* Wd = (d == 0) ? W0 + (size_t)l * 64 * IN_DIM
                        : (d == 1) ? W1 + (size_t)l * 4096
                                   : W2 + (size_t)l * 4096;
        const int K = (d == 0) ? IN_DIM : 64;
#pragma unroll
        for (int ks = 0; ks < 2; ++ks)
#pragma unroll
            for (int ct = 0; ct < 4; ++ct){
                float wf[8];
#pragma unroll
                for (int j = 0; j < 8; ++j){
                    const int s = ks * 32 + kb + j;
                    const int a = (d == 0) ? s : A_OF_SLOT(s);
                    wf[j] = Wd[(size_t)(ct * 16 + c) * K + a];
                }
                short8 wh, wl;
                split8v(wf, wh, wl);
                char* base = ws + (size_t)l * WBYTES + d * 16384 + (ks * 4 + ct) * 1024 + L * 16;
                *(short8*)base            = wh;
                *(short8*)(base + 8192)   = wl;
            }
    } else {                             // W3 fragments + w65 table
        const int l = b - 192;
#pragma unroll
        for (int ks = 0; ks < 2; ++ks){
            float wf[8];
#pragma unroll
            for (int j = 0; j < 8; ++j)
                wf[j] = (c == 0) ? W3[l * 64 + A_OF_SLOT(ks * 32 + kb + j)] : 0.0f;
            short8 wh, wl;
            split8v(wf, wh, wl);
            char* base = ws + (size_t)l * WBYTES + 49152 + ks * 1024 + L * 16;
            *(short8*)base          = wh;
            *(short8*)(base + 2048) = wl;
        }
        ((float*)(ws + W65_BYTE))[l * 64 + L] =
            W0[(size_t)l * 64 * IN_DIM + L * IN_DIM + 64];
    }
}

__global__ __launch_bounds__(512, 4)
void flow_mfma_kernel(const float* __restrict__ x,
                      const float* __restrict__ b0, const float* __restrict__ b1,
                      const float* __restrict__ b2, const float* __restrict__ b3,
                      const char* __restrict__ ws,
                      float* __restrict__ out_res, float* __restrict__ out_lad)
{
    __shared__ __attribute__((aligned(16))) char wlds[WBYTES];

    const int l   = blockIdx.y;
    const int tid = threadIdx.x;
    const int L   = tid & 63;
    const int wv  = tid >> 6;
    const int u   = L >> 4;
    const int g0  = blockIdx.x * RPB + wv * 16 + (L & 15);  // this lane's batch row

    // ---- stage this latent's 52KB weight block into LDS (8 waves cooperate) ----
    const char* gsrc = ws + (size_t)l * WBYTES;
#pragma unroll
    for (int i = 0; i < 7; ++i){
        const int base = i * 512 + wv * 64;          // wave-uniform chunk base
        if (base * 16 < WBYTES)
            __builtin_amdgcn_global_load_lds((GASU*)(gsrc + (base + L) * 16),
                                             (LASU*)(wlds + base * 16), 16, 0, 0);
    }

    // ---- per-lane x load at its own B-slots (overlap staging latency) ----
    const float* xg0 = x + ((size_t)g0 * LATENTS + l) * IN_DIM;
    float xv[16];
    float x65r;
#pragma unroll
    for (int j = 0; j < 8; ++j){
        xv[j]     = xg0[8 * u + j];
        xv[8 + j] = xg0[32 + 8 * u + j];
    }
    x65r = xg0[64];

    // ---- split x into B-frags (trunc hi / rhup lo) ----
    short8 bh[2], bl2[2], th2[2];
    split8t(&xv[0], bh[0], bl2[0]);
    split8t(&xv[8], bh[1], bl2[1]);

    __syncthreads();   // weights resident in LDS

    f32x4 ha[4], ta[4];

    // load all 4 column-tiles' fragments for one (d, ks)
    auto ldw4 = [&](int d, int ks, short8 (&wh)[4], short8 (&wl)[4]){
#pragma unroll
        for (int ct = 0; ct < 4; ++ct){
            const char* p = wlds + d * 16384 + (ks * 4 + ct) * 1024 + (L << 4);
            wh[ct] = *(const short8*)p;
            wl[ct] = *(const short8*)(p + 8192);
        }
    };
    // h-epilogue repack (channel->slot permutation, trunc hi / rhup lo)
    auto repack = [&](const float v[4][4], short8 (&hi)[2], short8 (&lo)[2]){
#pragma unroll
        for (int ks = 0; ks < 2; ++ks){
            float f8[8] = {v[ks][0], v[ks][1], v[ks][2], v[ks][3],
                           v[2 + ks][0], v[2 + ks][1], v[2 + ks][2], v[2 + ks][3]};
            split8t(f8, hi[ks], lo[ks]);
        }
    };
    // t-epilogue repack (rhup bf16 only)
    auto repackt = [&](const float v[4][4], short8 (&hi)[2]){
#pragma unroll
        for (int ks = 0; ks < 2; ++ks){
            float f8[8] = {v[ks][0], v[ks][1], v[ks][2], v[ks][3],
                           v[2 + ks][0], v[2 + ks][1], v[2 + ks][2], v[2 + ks][3]};
            hi[ks] = pack8r(f8);
        }
    };

    // ---- layer 0 (h only) + rank-1 col-64; tangent = mask * w65 ----
    {
#pragma unroll
        for (int ct = 0; ct < 4; ++ct)
            ha[ct] = __builtin_bit_cast(f32x4,
                        *(const float4*)(b0 + l * 64 + ct * 16 + u * 4));
#pragma unroll
        for (int ks = 0; ks < 2; ++ks){
            short8 wh[4], wl[4];
            ldw4(0, ks, wh, wl);
            __builtin_amdgcn_s_setprio(1);
            // phase-major: consecutive MFMAs hit different accumulators
#pragma unroll
            for (int ct = 0; ct < 4; ++ct) ha[ct] = mfma_(wh[ct], bh[ks],  ha[ct]);
#pragma unroll
            for (int ct = 0; ct < 4; ++ct) ha[ct] = mfma_(wh[ct], bl2[ks], ha[ct]);
#pragma unroll
            for (int ct = 0; ct < 4; ++ct) ha[ct] = mfma_(wl[ct], bh[ks],  ha[ct]);
            __builtin_amdgcn_s_setprio(0);
        }
        const float* w65p = (const float*)(ws + W65_BYTE) + l * 64;
        float hv[4][4], tv[4][4];
#pragma unroll
        for (int ct = 0; ct < 4; ++ct){
            const float4 wv4 = *(const float4*)(w65p + ct * 16 + u * 4);
            const float wa[4] = {wv4.x, wv4.y, wv4.z, wv4.w};
#pragma unroll
            for (int i = 0; i < 4; ++i){
                float z = fmaf(x65r, wa[i], ha[ct][i]);
                float m = (z >= 0.0f) ? 1.0f : SLOPE;
                hv[ct][i] = z * m;
                tv[ct][i] = wa[i] * m;
            }
        }
        repack(hv, bh, bl2);
        repackt(tv, th2);
    }

    // ---- layers 1,2: h (split) + t (bf16) GEMMs, weights JIT from LDS ----
    auto dense2 = [&](int d, const float* __restrict__ bl){
#pragma unroll
        for (int ct = 0; ct < 4; ++ct){
            ha[ct] = __builtin_bit_cast(f32x4,
                        *(const float4*)(bl + ct * 16 + u * 4));
            ta[ct] = (f32x4){0.f, 0.f, 0.f, 0.f};
        }
#pragma unroll
        for (int ks = 0; ks < 2; ++ks){
            short8 wh[4], wl[4];
            ldw4(d, ks, wh, wl);
            __builtin_amdgcn_s_setprio(1);
#pragma unroll
            for (int ct = 0; ct < 4; ++ct) ha[ct] = mfma_(wh[ct], bh[ks],  ha[ct]);
#pragma unroll
            for (int ct = 0; ct < 4; ++ct) ha[ct] = mfma_(wh[ct], bl2[ks], ha[ct]);
#pragma unroll
            for (int ct = 0; ct < 4; ++ct) ha[ct] = mfma_(wl[ct], bh[ks],  ha[ct]);
#pragma unroll
            for (int ct = 0; ct < 4; ++ct) ta[ct] = mfma_(wh[ct], th2[ks], ta[ct]);
#pragma unroll
            for (int ct = 0; ct < 4; ++ct) ta[ct] = mfma_(wl[ct], th2[ks], ta[ct]);
            __builtin_amdgcn_s_setprio(0);
        }
        float hv[4][4], tv[4][4];
#pragma unroll
        for (int ct = 0; ct < 4; ++ct)
#pragma unroll
            for (int i = 0; i < 4; ++i){
                float z  = ha[ct][i];
                float zt = ta[ct][i];
                float m  = (z >= 0.0f) ? 1.0f : SLOPE;
                hv[ct][i] = z * m;
                tv[ct][i] = zt * m;
            }
        repack(hv, bh, bl2);
        repackt(tv, th2);
    };
    dense2(1, b1 + l * 64);
    dense2(2, b2 + l * 64);

    // ---- layer 3: scalar head via MFMA (w3 in fragment col 0) ----
    {
        f32x4 so = (f32x4){0.f, 0.f, 0.f, 0.f};
        f32x4 sd = (f32x4){0.f, 0.f, 0.f, 0.f};
#pragma unroll
        for (int ks = 0; ks < 2; ++ks){
            const char* p = wlds + 49152 + ks * 1024 + (L << 4);
            short8 wh = *(const short8*)p;
            short8 wl = *(const short8*)(p + 2048);
            __builtin_amdgcn_s_setprio(1);
            // interleave the two accumulator chains
            so = mfma_(wh, bh[ks],  so);
            sd = mfma_(wh, th2[ks], sd);
            so = mfma_(wh, bl2[ks], so);
            sd = mfma_(wl, th2[ks], sd);
            so = mfma_(wl, bh[ks],  so);
            __builtin_amdgcn_s_setprio(0);
        }
        if (u == 0){   // D row 0 (lanes 0-15, reg 0); col = batch row
            out_res[(size_t)g0 * LATENTS + l] = so[0] + b3[l];
            atomicAdd(&out_lad[g0], __logf(fabsf(sd[0]) + FEPS));
        }
    }
}

extern "C" void kernel_launch(void* const* d_in, const int* in_sizes, int n_in,
                              void* d_out, int out_size, void* d_ws, size_t ws_size,
                              hipStream_t stream)
{
    const float* x  = (const float*)d_in[0];
    const float* W0 = (const float*)d_in[1];
    const float* b0 = (const float*)d_in[2];
    const float* W1 = (const float*)d_in[3];
    const float* b1 = (const float*)d_in[4];
    const float* W2 = (const float*)d_in[5];
    const float* b2 = (const float*)d_in[6];
    const float* W3 = (const float*)d_in[7];
    const float* b3 = (const float*)d_in[8];

    const int B = in_sizes[0] / (LATENTS * IN_DIM);  // 8192
    float* out_res = (float*)d_out;
    float* out_lad = out_res + (size_t)B * LATENTS;
    char*  wsp     = (char*)d_ws;   // 64*52KB frags + 16KB w65 = 3.27 MB

    w_prep_kernel<<<dim3(256 + (B + 63) / 64), dim3(64), 0, stream>>>(
        W0, W1, W2, W3, wsp, out_lad, B);
    flow_mfma_kernel<<<dim3(B / RPB, LATENTS), dim3(512), 0, stream>>>(
        x, b0, b1, b2, b3, wsp, out_res, out_lad);
}

// Round 18
// 72.369 us; speedup vs baseline: 1.1127x; 1.0109x over previous
//
#include <hip/hip_runtime.h>
#include <hip/hip_bf16.h>
#include <cmath>

#define LATENTS 64
#define HID 64
#define IN_DIM 65
#define SLOPE 0.2f
#define FEPS 1e-8f
#define RPB 128            // rows per block: 8 waves x 1 tile x 16 rows
#define WBYTES 51200       // per-latent: 3*16KB (W0-2 hi/lo) + 2KB (W3 hi only)
#define W65_BYTE (64 * WBYTES)

// channel a = act*16+au*4+ai  ->  slot s = (act&1)*32 + au*8 + (act>>1)*4 + ai
#define A_OF_SLOT(s) ((((((s) >> 2) & 1) * 2 + ((s) >> 5)) * 16) + ((((s) >> 3) & 3) * 4) + ((s) & 3))

typedef __attribute__((ext_vector_type(8))) short short8;
typedef __attribute__((ext_vector_type(4))) float f32x4;
typedef __attribute__((address_space(1))) const unsigned GASU;
typedef __attribute__((address_space(3))) unsigned LASU;

__device__ __forceinline__ unsigned asu(float f){ return __builtin_bit_cast(unsigned, f); }
__device__ __forceinline__ float    asf(unsigned u){ return __builtin_bit_cast(float, u); }
__device__ __forceinline__ unsigned bfu(float f){
    return (unsigned)__builtin_bit_cast(unsigned short, __float2bfloat16(f));
}

// w_prep split: hi = trunc16, lo = RTNE(remainder)  (W0-2, measured numerics)
__device__ __forceinline__ void split8v(const float* f, short8& hi, short8& lo){
    unsigned hw[4], lw[4];
#pragma unroll
    for (int w = 0; w < 4; ++w){
        float a = f[2 * w], b = f[2 * w + 1];
        unsigned ha = asu(a) & 0xFFFF0000u, hb = asu(b) & 0xFFFF0000u;
        float la = a - asf(ha), lb = b - asf(hb);
        hw[w] = (ha >> 16) | hb;
        lw[w] = bfu(la) | (bfu(lb) << 16);
    }
    uint4 h4{hw[0], hw[1], hw[2], hw[3]}, l4{lw[0], lw[1], lw[2], lw[3]};
    hi = __builtin_bit_cast(short8, h4);
    lo = __builtin_bit_cast(short8, l4);
}

// RTNE pack (W3 hi storage — must be unbiased since used alone)
__device__ __forceinline__ short8 pack8v(const float* f){
    unsigned w[4];
#pragma unroll
    for (int i = 0; i < 4; ++i)
        w[i] = bfu(f[2 * i]) | (bfu(f[2 * i + 1]) << 16);
    uint4 p{w[0], w[1], w[2], w[3]};
    return __builtin_bit_cast(short8, p);
}

// hot path: hi = trunc16(f), lo = round-half-up16(f - hi)
__device__ __forceinline__ void split8t(const float* f, short8& hi, short8& lo){
    unsigned hw[4], lw[4];
#pragma unroll
    for (int w = 0; w < 4; ++w){
        float a = f[2 * w], b = f[2 * w + 1];
        float la = a - asf(asu(a) & 0xFFFF0000u);
        float lb = b - asf(asu(b) & 0xFFFF0000u);
        hw[w] = __builtin_amdgcn_perm(asu(b), asu(a), 0x07060302u);
        lw[w] = __builtin_amdgcn_perm(asu(lb) + 0x8000u, asu(la) + 0x8000u, 0x07060302u);
    }
    uint4 h4{hw[0], hw[1], hw[2], hw[3]}, l4{lw[0], lw[1], lw[2], lw[3]};
    hi = __builtin_bit_cast(short8, h4);
    lo = __builtin_bit_cast(short8, l4);
}

// round-half-up pack (tangent storage): add + perm per pair
__device__ __forceinline__ short8 pack8r(const float* f){
    unsigned w[4];
#pragma unroll
    for (int i = 0; i < 4; ++i)
        w[i] = __builtin_amdgcn_perm(asu(f[2 * i + 1]) + 0x8000u,
                                     asu(f[2 * i])     + 0x8000u, 0x07060302u);
    uint4 p{w[0], w[1], w[2], w[3]};
    return __builtin_bit_cast(short8, p);
}

__device__ __forceinline__ f32x4 mfma_(short8 a, short8 b, f32x4 c){
    return __builtin_amdgcn_mfma_f32_16x16x32_bf16(a, b, c, 0, 0, 0);
}

// Pre-split all weights into bf16 MFMA fragments (50KB/latent), and zero-init
// the logabsdet output (blocks 256..383) — one launch does both.
__global__ __launch_bounds__(64)
void w_prep_kernel(const float* __restrict__ W0, const float* __restrict__ W1,
                   const float* __restrict__ W2, const float* __restrict__ W3,
                   char* __restrict__ ws, float* __restrict__ lad, int B)
{
    const int b = blockIdx.x;
    const int L = threadIdx.x;
    const int c  = L & 15;
    const int kb = (L >> 4) * 8;
    if (b >= 256){                       // lad zero-init
        const int i = (b - 256) * 64 + L;
        if (i < B) lad[i] = 0.0f;
        return;
    }
    if (b < 192){                        // W0/W1/W2 fragments (hi + lo)
        const int l = b / 3, d = b - 3 * l;
        const float* Wd = (d == 0) ? W0 + (size_t)l * 64 * IN_DIM
                        : (d == 1) ? W1 + (size_t)l * 4096
                                   : W2 + (size_t)l * 4096;
        const int K = (d == 0) ? IN_DIM : 64;
#pragma unroll
        for (int ks = 0; ks < 2; ++ks)
#pragma unroll
            for (int ct = 0; ct < 4; ++ct){
                float wf[8];
#pragma unroll
                for (int j = 0; j < 8; ++j){
                    const int s = ks * 32 + kb + j;
                    const int a = (d == 0) ? s : A_OF_SLOT(s);
                    wf[j] = Wd[(size_t)(ct * 16 + c) * K + a];
                }
                short8 wh, wl;
                split8v(wf, wh, wl);
                char* base = ws + (size_t)l * WBYTES + d * 16384 + (ks * 4 + ct) * 1024 + L * 16;
                *(short8*)base            = wh;
                *(short8*)(base + 8192)   = wl;
            }
    } else {                             // W3 fragments (RTNE hi only) + w65 table
        const int l = b - 192;
#pragma unroll
        for (int ks = 0; ks < 2; ++ks){
            float wf[8];
#pragma unroll
            for (int j = 0; j < 8; ++j)
                wf[j] = (c == 0) ? W3[l * 64 + A_OF_SLOT(ks * 32 + kb + j)] : 0.0f;
            char* base = ws + (size_t)l * WBYTES + 49152 + ks * 1024 + L * 16;
            *(short8*)base = pack8v(wf);
        }
        ((float*)(ws + W65_BYTE))[l * 64 + L] =
            W0[(size_t)l * 64 * IN_DIM + L * IN_DIM + 64];
    }
}

__global__ __launch_bounds__(512, 4)
void flow_mfma_kernel(const float* __restrict__ x,
                      const float* __restrict__ b0, const float* __restrict__ b1,
                      const float* __restrict__ b2, const float* __restrict__ b3,
                      const char* __restrict__ ws,
                      float* __restrict__ out_res, float* __restrict__ out_lad)
{
    __shared__ __attribute__((aligned(16))) char wlds[WBYTES];

    const int l   = blockIdx.y;
    const int tid = threadIdx.x;
    const int L   = tid & 63;
    const int wv  = tid >> 6;
    const int u   = L >> 4;
    const int g0  = blockIdx.x * RPB + wv * 16 + (L & 15);  // this lane's batch row

    // ---- stage this latent's 50KB weight block into LDS (8 waves cooperate) ----
    const char* gsrc = ws + (size_t)l * WBYTES;
#pragma unroll
    for (int i = 0; i < 7; ++i){
        const int base = i * 512 + wv * 64;          // wave-uniform chunk base
        if (base * 16 < WBYTES)
            __builtin_amdgcn_global_load_lds((GASU*)(gsrc + (base + L) * 16),
                                             (LASU*)(wlds + base * 16), 16, 0, 0);
    }

    // ---- per-lane x load at its own B-slots (overlap staging latency) ----
    const float* xg0 = x + ((size_t)g0 * LATENTS + l) * IN_DIM;
    float xv[16];
    float x65r;
#pragma unroll
    for (int j = 0; j < 8; ++j){
        xv[j]     = xg0[8 * u + j];
        xv[8 + j] = xg0[32 + 8 * u + j];
    }
    x65r = xg0[64];

    // ---- split x into B-frags (trunc hi / rhup lo) ----
    short8 bh[2], bl2[2], th2[2];
    split8t(&xv[0], bh[0], bl2[0]);
    split8t(&xv[8], bh[1], bl2[1]);

    __syncthreads();   // weights resident in LDS

    f32x4 ha[4], ta[4];

    // load all 4 column-tiles' fragments for one (d, ks)
    auto ldw4 = [&](int d, int ks, short8 (&wh)[4], short8 (&wl)[4]){
#pragma unroll
        for (int ct = 0; ct < 4; ++ct){
            const char* p = wlds + d * 16384 + (ks * 4 + ct) * 1024 + (L << 4);
            wh[ct] = *(const short8*)p;
            wl[ct] = *(const short8*)(p + 8192);
        }
    };
    // h-epilogue repack (channel->slot permutation, trunc hi / rhup lo)
    auto repack = [&](const float v[4][4], short8 (&hi)[2], short8 (&lo)[2]){
#pragma unroll
        for (int ks = 0; ks < 2; ++ks){
            float f8[8] = {v[ks][0], v[ks][1], v[ks][2], v[ks][3],
                           v[2 + ks][0], v[2 + ks][1], v[2 + ks][2], v[2 + ks][3]};
            split8t(f8, hi[ks], lo[ks]);
        }
    };
    // t-epilogue repack (rhup bf16 only)
    auto repackt = [&](const float v[4][4], short8 (&hi)[2]){
#pragma unroll
        for (int ks = 0; ks < 2; ++ks){
            float f8[8] = {v[ks][0], v[ks][1], v[ks][2], v[ks][3],
                           v[2 + ks][0], v[2 + ks][1], v[2 + ks][2], v[2 + ks][3]};
            hi[ks] = pack8r(f8);
        }
    };

    // ---- layer 0 (h only) + rank-1 col-64; tangent = mask * w65 ----
    {
#pragma unroll
        for (int ct = 0; ct < 4; ++ct)
            ha[ct] = __builtin_bit_cast(f32x4,
                        *(const float4*)(b0 + l * 64 + ct * 16 + u * 4));
#pragma unroll
        for (int ks = 0; ks < 2; ++ks){
            short8 wh[4], wl[4];
            ldw4(0, ks, wh, wl);
            __builtin_amdgcn_s_setprio(1);
            // phase-major: consecutive MFMAs hit different accumulators
#pragma unroll
            for (int ct = 0; ct < 4; ++ct) ha[ct] = mfma_(wh[ct], bh[ks],  ha[ct]);
#pragma unroll
            for (int ct = 0; ct < 4; ++ct) ha[ct] = mfma_(wh[ct], bl2[ks], ha[ct]);
#pragma unroll
            for (int ct = 0; ct < 4; ++ct) ha[ct] = mfma_(wl[ct], bh[ks],  ha[ct]);
            __builtin_amdgcn_s_setprio(0);
        }
        const float* w65p = (const float*)(ws + W65_BYTE) + l * 64;
        float hv[4][4], tv[4][4];
#pragma unroll
        for (int ct = 0; ct < 4; ++ct){
            const float4 wv4 = *(const float4*)(w65p + ct * 16 + u * 4);
            const float wa[4] = {wv4.x, wv4.y, wv4.z, wv4.w};
#pragma unroll
            for (int i = 0; i < 4; ++i){
                float z = fmaf(x65r, wa[i], ha[ct][i]);
                float m = (z >= 0.0f) ? 1.0f : SLOPE;
                hv[ct][i] = z * m;
                tv[ct][i] = wa[i] * m;
            }
        }
        repack(hv, bh, bl2);
        repackt(tv, th2);
    }

    // ---- layers 1,2: h (split) + t (bf16) GEMMs, weights JIT from LDS ----
    auto dense2 = [&](int d, const float* __restrict__ bl){
#pragma unroll
        for (int ct = 0; ct < 4; ++ct){
            ha[ct] = __builtin_bit_cast(f32x4,
                        *(const float4*)(bl + ct * 16 + u * 4));
            ta[ct] = (f32x4){0.f, 0.f, 0.f, 0.f};
        }
#pragma unroll
        for (int ks = 0; ks < 2; ++ks){
            short8 wh[4], wl[4];
            ldw4(d, ks, wh, wl);
            __builtin_amdgcn_s_setprio(1);
#pragma unroll
            for (int ct = 0; ct < 4; ++ct) ha[ct] = mfma_(wh[ct], bh[ks],  ha[ct]);
#pragma unroll
            for (int ct = 0; ct < 4; ++ct) ha[ct] = mfma_(wh[ct], bl2[ks], ha[ct]);
#pragma unroll
            for (int ct = 0; ct < 4; ++ct) ha[ct] = mfma_(wl[ct], bh[ks],  ha[ct]);
#pragma unroll
            for (int ct = 0; ct < 4; ++ct) ta[ct] = mfma_(wh[ct], th2[ks], ta[ct]);
#pragma unroll
            for (int ct = 0; ct < 4; ++ct) ta[ct] = mfma_(wl[ct], th2[ks], ta[ct]);
            __builtin_amdgcn_s_setprio(0);
        }
        float hv[4][4], tv[4][4];
#pragma unroll
        for (int ct = 0; ct < 4; ++ct)
#pragma unroll
            for (int i = 0; i < 4; ++i){
                float z  = ha[ct][i];
                float zt = ta[ct][i];
                float m  = (z >= 0.0f) ? 1.0f : SLOPE;
                hv[ct][i] = z * m;
                tv[ct][i] = zt * m;
            }
        repack(hv, bh, bl2);
        repackt(tv, th2);
    };
    dense2(1, b1 + l * 64);
    dense2(2, b2 + l * 64);

    // ---- layer 3: scalar head via MFMA (W3 hi only — lo terms ~2^-9, dropped) ----
    {
        f32x4 so = (f32x4){0.f, 0.f, 0.f, 0.f};
        f32x4 sd = (f32x4){0.f, 0.f, 0.f, 0.f};
#pragma unroll
        for (int ks = 0; ks < 2; ++ks){
            const char* p = wlds + 49152 + ks * 1024 + (L << 4);
            short8 wh = *(const short8*)p;
            __builtin_amdgcn_s_setprio(1);
            so = mfma_(wh, bh[ks],  so);
            sd = mfma_(wh, th2[ks], sd);
            so = mfma_(wh, bl2[ks], so);
            __builtin_amdgcn_s_setprio(0);
        }
        if (u == 0){   // D row 0 (lanes 0-15, reg 0); col = batch row
            out_res[(size_t)g0 * LATENTS + l] = so[0] + b3[l];
            atomicAdd(&out_lad[g0], __logf(fabsf(sd[0]) + FEPS));
        }
    }
}

extern "C" void kernel_launch(void* const* d_in, const int* in_sizes, int n_in,
                              void* d_out, int out_size, void* d_ws, size_t ws_size,
                              hipStream_t stream)
{
    const float* x  = (const float*)d_in[0];
    const float* W0 = (const float*)d_in[1];
    const float* b0 = (const float*)d_in[2];
    const float* W1 = (const float*)d_in[3];
    const float* b1 = (const float*)d_in[4];
    const float* W2 = (const float*)d_in[5];
    const float* b2 = (const float*)d_in[6];
    const float* W3 = (const float*)d_in[7];
    const float* b3 = (const float*)d_in[8];

    const int B = in_sizes[0] / (LATENTS * IN_DIM);  // 8192
    float* out_res = (float*)d_out;
    float* out_lad = out_res + (size_t)B * LATENTS;
    char*  wsp     = (char*)d_ws;   // 64*50KB frags + 16KB w65 = 3.29 MB

    w_prep_kernel<<<dim3(256 + (B + 63) / 64), dim3(64), 0, stream>>>(
        W0, W1, W2, W3, wsp, out_lad, B);
    flow_mfma_kernel<<<dim3(B / RPB, LATENTS), dim3(512), 0, stream>>>(
        x, b0, b1, b2, b3, wsp, out_res, out_lad);
}